// Round 10
// baseline (389.176 us; speedup 1.0000x reference)
//
#include <hip/hip_runtime.h>
#include <hip/hip_bf16.h>

#define NLAYERS 3
#define BB 32
#define LL 336
#define LP 352                 // K-padded stride for Tb16 / p1wb (zeros in pad)
#define NN 321
#define EE 4
#define DHID 512
#define PP 96
#define STOT (BB*NN*LL)        // 3451392
#define MROWS (BB*NN)          // 10272
#define BPN ((size_t)BB*PP*NN) // 986112

// fragment-contiguous weight layouts:
// W1f[e][nf=32][ks=11][lane=64][8]  (frag stride 5632, e stride 180224)
// W2f[e][nf=21][ks=16][lane=64][8]  (frag stride 8192, e stride 172032)
#define F1S 5632
#define E1S 180224
#define F2S 8192
#define E2S 172032

typedef __attribute__((ext_vector_type(8))) short short8;
typedef __attribute__((ext_vector_type(4))) float float4v;

union BF { __hip_bfloat16 h; short s; };

__device__ __forceinline__ short f2b(float f) { BF u; u.h = __float2bfloat16(f); return u.s; }

__device__ __forceinline__ float fast_tanh(float y) {
    float e = __expf(2.0f * y);
    return 1.0f - 2.0f / (e + 1.0f);   // exact limits at +-inf
}
__device__ __forceinline__ float gelu_f(float x) {
    return 0.5f * x * (1.0f + fast_tanh(0.7978845608028654f * (x + 0.044715f * x * x * x)));
}
__device__ __forceinline__ float softplus_f(float x) {
    return fmaxf(x, 0.0f) + log1pf(expf(-fabsf(x)));
}

// ---------------- prep: weight transpose->fragment layout + pcvt + RevIN stats + zeroing ----------------
__global__ __launch_bounds__(256) void prep_kernel(
    const float* __restrict__ x, const float* __restrict__ W1, const float* __restrict__ W2,
    const float* __restrict__ p1w, const float* __restrict__ p2w,
    float* __restrict__ MU, float* __restrict__ IV, float* __restrict__ LOSS,
    float* __restrict__ G0, short* __restrict__ W1f, short* __restrict__ W2f,
    short* __restrict__ p1wb, short* __restrict__ p2wb)
{
    __shared__ short Ws[64][72];
    __shared__ float Ss[4][64], Sq[4][64];
    int idx = blockIdx.x, tid = threadIdx.x;
    if (idx < 1152) {
        const float* src; int K, D, KS, bx, by, le;
        if (idx < 576) {
            le = idx / 48; int r = idx % 48;
            src = W1 + (size_t)le * LL * DHID;
            K = LL; D = DHID; KS = LP; bx = r % 8; by = r / 8;
        } else {
            int s2 = idx - 576; le = s2 / 48; int r = s2 % 48;
            src = W2 + (size_t)le * DHID * LL;
            K = DHID; D = LL; KS = DHID; bx = r % 6; by = r / 6;
        }
        int d0 = bx * 64, k0 = by * 64;
        // vectorized stage: 4 iterations of float4 per thread (64x64 tile)
        #pragma unroll
        for (int it = 0; it < 4; ++it) {
            int ki = (tid >> 4) + it * 16;
            int dj = (tid & 15) * 4;
            int k = k0 + ki, d = d0 + dj;
            float4 v = make_float4(0.f, 0.f, 0.f, 0.f);
            if (k < K) {
                const float* sp = src + (size_t)k * D + d;
                if (d + 3 < D) v = *(const float4*)sp;
                else {
                    if (d     < D) v.x = sp[0];
                    if (d + 1 < D) v.y = sp[1];
                    if (d + 2 < D) v.z = sp[2];
                    if (d + 3 < D) v.w = sp[3];
                }
            }
            union { short s[4]; uint2 u; } pk4;
            pk4.s[0] = f2b(v.x); pk4.s[1] = f2b(v.y); pk4.s[2] = f2b(v.z); pk4.s[3] = f2b(v.w);
            *(uint2*)&Ws[ki][dj] = pk4.u;
        }
        __syncthreads();
        int di = tid >> 2, d = d0 + di;
        if (d >= D) return;
        #pragma unroll
        for (int kp = 0; kp < 2; ++kp) {
            int kj = ((tid & 3) + 4 * kp) * 8;
            int k = k0 + kj;
            if (k >= KS) continue;
            union { short s[8]; uint4 u; } pk;
            #pragma unroll
            for (int j = 0; j < 8; ++j) pk.s[j] = Ws[kj + j][di];
            int nf = d >> 4;
            int ks = k >> 5;
            int l  = (((k >> 3) & 3) << 4) | (d & 15);
            if (idx < 576) {   // W1f: [le][nf][ks(11)][l][8]
                size_t o = (size_t)le * E1S + ((size_t)(nf * 11 + ks) * 64 + l) * 8;
                *(uint4*)&W1f[o] = pk.u;
            } else {           // W2f: [le][nf][ks(16)][l][8]
                size_t o = (size_t)le * E2S + ((size_t)(nf * 16 + ks) * 64 + l) * 8;
                *(uint4*)&W2f[o] = pk.u;
            }
        }
    } else if (idx < 1344) {
        int q = idx - 1152;
        int b = q / 6, nt = q % 6;
        if (tid < 56) G0[q * 56 + tid] = 0.0f;      // 192*56 = BB*LL exactly
        if (q == 0 && tid < 8) LOSS[tid] = 0.0f;
        int ni = tid & 63, lc = tid >> 6;
        int n = nt * 64 + ni;
        float s = 0.f, ss = 0.f;
        if (n < NN) {
            const float* xp = x + ((size_t)b * LL + lc * 84) * NN + n;
            for (int l = 0; l < 84; ++l, xp += NN) {
                float v = *xp; s += v; ss = fmaf(v, v, ss);
            }
        }
        Ss[lc][ni] = s; Sq[lc][ni] = ss;
        __syncthreads();
        if (lc == 0 && n < NN) {
            float st = ((Ss[0][ni] + Ss[1][ni]) + Ss[2][ni]) + Ss[3][ni];
            float sq = ((Sq[0][ni] + Sq[1][ni]) + Sq[2][ni]) + Sq[3][ni];
            float mu  = st * (1.0f / LL);
            float var = sq * (1.0f / LL) - mu * mu;   // ddof=0
            MU[b * NN + n] = mu;
            IV[b * NN + n] = 1.0f / sqrtf(var + 1e-5f);
        }
    } else {
        int i = (idx - 1344) * 256 + tid;
        if (i < PP * LP) {
            int n = i / LP, k = i - n * LP;
            p1wb[i] = (k < LL) ? f2b(p1w[n * LL + k]) : (short)0;
        } else if (i < PP * LP + 2 * PP * PP) {
            int j = i - PP * LP;
            p2wb[j] = f2b(p2w[j]);
        }
    }
}

// ---------------- RevIN transpose+normalize + layer-0 gate-sum accumulation ----------------
__global__ __launch_bounds__(256) void revin_tn(
    const float* __restrict__ x, const float* __restrict__ MU, const float* __restrict__ IV,
    float* __restrict__ T, short* __restrict__ Tb16, float* __restrict__ G0)
{
    int b = blockIdx.x, nt = blockIdx.y, lt = blockIdx.z;
    int n0 = nt * 64, l0 = lt * 48;
    __shared__ float Ls[48][65];
    __shared__ float Vs[48][65];
    int tid = threadIdx.x;
    #pragma unroll
    for (int i = 0; i < 12; ++i) {
        int lin = tid + i * 256;
        int li = lin >> 6, ni = lin & 63;
        int n = n0 + ni;
        Ls[li][ni] = (n < NN) ? x[((size_t)b * LL + l0 + li) * NN + n] : 0.f;
    }
    __syncthreads();
    int r = tid >> 2, q = tid & 3;
    int n = n0 + r;
    bool valid = (n < NN);
    float mu = 0.f, iv = 0.f;
    if (valid) { mu = MU[b * NN + n]; iv = IV[b * NN + n]; }
    size_t rowf = (size_t)(b * NN + (valid ? n : 0)) * LL + l0;
    size_t rowb = (size_t)(b * NN + (valid ? n : 0)) * LP + l0;
    #pragma unroll
    for (int k = 0; k < 3; ++k) {
        int c = (q + 4 * k) * 4;
        float4 v;
        v.x = (Ls[c    ][r] - mu) * iv;
        v.y = (Ls[c + 1][r] - mu) * iv;
        v.z = (Ls[c + 2][r] - mu) * iv;
        v.w = (Ls[c + 3][r] - mu) * iv;
        Vs[c][r] = v.x; Vs[c + 1][r] = v.y; Vs[c + 2][r] = v.z; Vs[c + 3][r] = v.w;
        if (valid) {
            *(float4*)&T[rowf + c] = v;
            union { short s[4]; uint2 u; } pk;
            pk.s[0] = f2b(v.x); pk.s[1] = f2b(v.y); pk.s[2] = f2b(v.z); pk.s[3] = f2b(v.w);
            *(uint2*)&Tb16[rowb + c] = pk.u;
        }
    }
    if (valid && lt == 6 && q == 3) {   // zero the K-pad cols 336..352
        size_t base = (size_t)(b * NN + n) * LP;
        *(uint4*)&Tb16[base + 336] = make_uint4(0, 0, 0, 0);
        *(uint4*)&Tb16[base + 344] = make_uint4(0, 0, 0, 0);
    }
    __syncthreads();
    if (tid < 48) {   // column sums over this block's 64 nodes -> G0 (SUMS, zeroed by prep)
        float s = 0.f;
        #pragma unroll 8
        for (int rr = 0; rr < 64; ++rr) s += Vs[tid][rr];
        unsafeAtomicAdd(&G0[b * LL + l0 + tid], s);
    }
}

// ---------------- loss scratch (aliases fc1's A-tile LDS) ----------------
struct LossSM {
    float pc2[BB][EE][2], pn2[BB][EE][2];
    float sc[BB][EE], sn[BB][EE], sy[BB][EE], sg[BB][EE];
    float sti[BB], sto[BB];
    float simp[EE], sload[EE];
};

// full-batch aux loss; 256-thread block. Leading barrier protects the alias.
// (Gnext zeroing is spread across fc1 blocks i<42, NOT here.)
__device__ void loss_tail(LossSM* S, const float* __restrict__ Gcur,
                          const float* __restrict__ wgL, const float* __restrict__ wnL,
                          const float* __restrict__ noiseL, float* __restrict__ LOSS, int tid)
{
    __syncthreads();
    {
        int bb = tid >> 3, ee = (tid >> 1) & 3, sub = tid & 1;
        float c = 0.f, nr = 0.f;
        const float* gp = Gcur + bb * LL;
        for (int l = sub * 168; l < sub * 168 + 168; ++l) {
            float gv = gp[l] * (1.0f / NN);
            c  = fmaf(gv, wgL[l * EE + ee], c);
            nr = fmaf(gv, wnL[l * EE + ee], nr);
        }
        S->pc2[bb][ee][sub] = c; S->pn2[bb][ee][sub] = nr;
    }
    __syncthreads();
    if (tid < 128) {
        int bb = tid >> 2, ee = tid & 3;
        float c  = S->pc2[bb][ee][0] + S->pc2[bb][ee][1];
        float nr = S->pn2[bb][ee][0] + S->pn2[bb][ee][1];
        float ns = softplus_f(nr) + 1e-2f;
        S->sc[bb][ee] = c; S->sn[bb][ee] = ns;
        S->sy[bb][ee] = fmaf(noiseL[bb * EE + ee], ns, c);
    }
    __syncthreads();
    if (tid < 128 && (tid & 3) == 0) {
        int bb = tid >> 2;
        float v[4];
        #pragma unroll
        for (int i = 0; i < 4; ++i) v[i] = S->sy[bb][i];
        int i0 = 0;
        for (int i = 1; i < 4; ++i) if (v[i] > v[i0]) i0 = i;
        int i1 = -1;
        for (int i = 0; i < 4; ++i) { if (i == i0) continue; if (i1 < 0 || v[i] > v[i1]) i1 = i; }
        float m3 = -1e30f;
        for (int i = 0; i < 4; ++i) { if (i == i0 || i == i1) continue; if (v[i] > m3) m3 = v[i]; }
        float e1 = expf(v[i1] - v[i0]);
        float invd = 1.0f / (1.0f + e1);
        #pragma unroll
        for (int i = 0; i < 4; ++i) S->sg[bb][i] = 0.f;
        S->sg[bb][i0] = invd;
        S->sg[bb][i1] = e1 * invd;
        S->sti[bb] = m3;       // (k+1)-th value
        S->sto[bb] = v[i1];    // k-th value
    }
    __syncthreads();
    if (tid < EE) {
        int ee = tid;
        float imp = 0.f, ld = 0.f;
        for (int bb2 = 0; bb2 < BB; ++bb2) {
            imp += S->sg[bb2][ee];
            float thr = (S->sy[bb2][ee] > S->sti[bb2]) ? S->sti[bb2] : S->sto[bb2];
            float z = (S->sc[bb2][ee] - thr) / S->sn[bb2][ee];
            ld += 0.5f * (1.0f + erff(z * 0.7071067811865476f));
        }
        S->simp[ee] = imp; S->sload[ee] = ld;
    }
    __syncthreads();
    if (tid == 0) {
        float aux = 0.f;
        {
            float m = (S->simp[0] + S->simp[1] + S->simp[2] + S->simp[3]) * 0.25f;
            float var = 0.f;
            for (int i = 0; i < 4; ++i) { float d = S->simp[i] - m; var += d * d; }
            var *= (1.0f / 3.0f);
            aux += var / (m * m + 1e-10f);
        }
        {
            float m = (S->sload[0] + S->sload[1] + S->sload[2] + S->sload[3]) * 0.25f;
            float var = 0.f;
            for (int i = 0; i < 4; ++i) { float d = S->sload[i] - m; var += d * d; }
            var *= (1.0f / 3.0f);
            aux += var / (m * m + 1e-10f);
        }
        LOSS[0] += 0.01f * aux;
    }
}

// ---------------- FC1: 32-row tiles, BOTH slots per block (amortized prologue) ----------------
// flat grid 704 = 2 xt x 11 y x 32 b (XCD-swizzled). n0 = xt*256, acc 2x4, slot-loop.
__global__ __launch_bounds__(256, 4) void fc1_mfma(
    const short* __restrict__ Tb16, const short* __restrict__ W1f_l,
    const float* __restrict__ b1_l,
    const float* __restrict__ Gcur, float* __restrict__ Gnext,
    const float* __restrict__ wgL, const float* __restrict__ wnL,
    const float* __restrict__ noiseL,
    int* __restrict__ IDX, float* __restrict__ GV,
    short* __restrict__ Hs, float* __restrict__ LOSS)
{
    int i = blockIdx.x;
    int low = i & 7, rest = i >> 3;
    int xt = rest & 1, ghi = rest >> 1;      // xt in [0,2), ghi in [0,44)
    int g = ghi * 8 + low;                   // [0,352)
    int y = g % 11, b = g / 11;
    int m0 = y * 32, n0 = xt * 256;
    int tid = threadIdx.x;
    int wave = tid >> 6, lane = tid & 63, quad = lane >> 4, l16 = lane & 15;
    __shared__ __align__(16) short Al[32][360];   // stride 720B -> ~2-way banks (23 KB)
    __shared__ float redc[4][4], redn[4][4];
    // spread Gnext zeroing across 42 blocks (42*256 = BB*LL), overlapped with staging
    if (i < 42) Gnext[i * 256 + tid] = 0.0f;
    {   // stage 32 x 352 A tile: 1408 uint4; clamp rows >= NN to NN-1 (avoid slack reads)
        #pragma unroll
        for (int it = 0; it < 6; ++it) {
            int idx = tid + it * 256;
            if (idx < 1408) {
                int r = idx / 44, c = (idx - r * 44) * 8;
                int gr = m0 + r; if (gr > NN - 1) gr = NN - 1;
                *(uint4*)&Al[r][c] = *(const uint4*)(Tb16 + ((size_t)b * NN + gr) * LP + c);
            }
        }
    }
    // gating partials: ALL threads (l = tid, tid+256), wave-reduce -> LDS
    {
        float pce[4] = {0.f,0.f,0.f,0.f}, pne[4] = {0.f,0.f,0.f,0.f};
        const float* gp = Gcur + b * LL;
        #pragma unroll
        for (int pass = 0; pass < 2; ++pass) {
            int l = tid + pass * 256;
            if (l < LL) {
                float gv = gp[l] * (1.0f / NN);
                #pragma unroll
                for (int e2 = 0; e2 < 4; ++e2) {
                    pce[e2] = fmaf(gv, wgL[l * EE + e2], pce[e2]);
                    pne[e2] = fmaf(gv, wnL[l * EE + e2], pne[e2]);
                }
            }
        }
        #pragma unroll
        for (int off = 32; off >= 1; off >>= 1) {
            #pragma unroll
            for (int e2 = 0; e2 < 4; ++e2) {
                pce[e2] += __shfl_xor(pce[e2], off);
                pne[e2] += __shfl_xor(pne[e2], off);
            }
        }
        if (lane == 0) {
            #pragma unroll
            for (int e2 = 0; e2 < 4; ++e2) { redc[wave][e2] = pce[e2]; redn[wave][e2] = pne[e2]; }
        }
    }
    __syncthreads();
    // redundant per-thread finalize (deterministic -> uniform)
    int i0, i1; float gtv0, gtv1;
    {
        float vv[4];
        #pragma unroll
        for (int e2 = 0; e2 < 4; ++e2) {
            float c  = ((redc[0][e2] + redc[1][e2]) + redc[2][e2]) + redc[3][e2];
            float nr = ((redn[0][e2] + redn[1][e2]) + redn[2][e2]) + redn[3][e2];
            float ns = softplus_f(nr) + 1e-2f;
            vv[e2] = fmaf(noiseL[b * EE + e2], ns, c);
        }
        i0 = 0;
        #pragma unroll
        for (int e2 = 1; e2 < 4; ++e2) if (vv[e2] > vv[i0]) i0 = e2;
        i1 = -1;
        #pragma unroll
        for (int e2 = 0; e2 < 4; ++e2) { if (e2 == i0) continue; if (i1 < 0 || vv[e2] > vv[i1]) i1 = e2; }
        float e1v = expf(vv[i1] - vv[i0]);
        float invd = 1.0f / (1.0f + e1v);
        gtv0 = invd; gtv1 = e1v * invd;
        if (y == 0 && xt == 0 && tid == 0) {   // publish for fc2 (one block per b)
            IDX[2 * b] = i0; IDX[2 * b + 1] = i1;
            GV[2 * b] = gtv0; GV[2 * b + 1] = gtv1;
        }
    }

    int wn4 = wave * 64;
    float4v zero4 = {0.f, 0.f, 0.f, 0.f};
    #pragma unroll 1
    for (int slot = 0; slot < 2; ++slot) {
        int e = slot ? i1 : i0;
        float gt = slot ? gtv1 : gtv0;
        // B fragments: wave-contiguous 1KB reads, depth-1 prefetch. nf = xt*16 + wave*4 + ni
        const short* Bf = W1f_l + (size_t)(e * 32 + xt * 16 + wave * 4) * F1S + lane * 8;
        float4v acc[2][4];
        #pragma unroll
        for (int a = 0; a < 2; ++a)
            #pragma unroll
            for (int j = 0; j < 4; ++j) acc[a][j] = zero4;

        short8 bc[4];
        #pragma unroll
        for (int j = 0; j < 4; ++j) bc[j] = *(const short8*)(Bf + j * F1S);
        #pragma unroll
        for (int ks = 0; ks < 11; ++ks) {
            short8 bn[4];
            if (ks < 10) {
                int o = (ks + 1) * 512;
                #pragma unroll
                for (int j = 0; j < 4; ++j) bn[j] = *(const short8*)(Bf + j * F1S + o);
            }
            int off = ks * 32;
            short8 af[2];
            #pragma unroll
            for (int mi = 0; mi < 2; ++mi) af[mi] = *(const short8*)&Al[mi * 16 + l16][off + quad * 8];
            #pragma unroll
            for (int mi = 0; mi < 2; ++mi) {
                acc[mi][0] = __builtin_amdgcn_mfma_f32_16x16x32_bf16(af[mi], bc[0], acc[mi][0], 0, 0, 0);
                acc[mi][1] = __builtin_amdgcn_mfma_f32_16x16x32_bf16(af[mi], bc[1], acc[mi][1], 0, 0, 0);
                acc[mi][2] = __builtin_amdgcn_mfma_f32_16x16x32_bf16(af[mi], bc[2], acc[mi][2], 0, 0, 0);
                acc[mi][3] = __builtin_amdgcn_mfma_f32_16x16x32_bf16(af[mi], bc[3], acc[mi][3], 0, 0, 0);
            }
            if (ks < 10) {
                #pragma unroll
                for (int j = 0; j < 4; ++j) bc[j] = bn[j];
            }
        }
        const float* bb = b1_l + (size_t)e * DHID;
        float bias[4];
        #pragma unroll
        for (int ni = 0; ni < 4; ++ni) bias[ni] = bb[n0 + wn4 + ni * 16 + l16];
        short* Ho = Hs + (size_t)(b * 2 + slot) * NN * DHID;
        #pragma unroll
        for (int mi = 0; mi < 2; ++mi) {
            #pragma unroll
            for (int r = 0; r < 4; ++r) {
                int gm = m0 + mi * 16 + quad * 4 + r;   // C/D: col=lane&15, row=quad*4+reg
                if (gm >= NN) continue;
                #pragma unroll
                for (int ni = 0; ni < 4; ++ni) {
                    int gd = n0 + wn4 + ni * 16 + l16;
                    float vv = acc[mi][ni][r] + bias[ni];
                    Ho[(size_t)gm * DHID + gd] = f2b(gt * gelu_f(vv));
                }
            }
        }
    }
    if (i == 0) loss_tail((LossSM*)&Al[0][0], Gcur, wgL, wnL, noiseL, LOSS, tid);
}

// ---------------- FC2: 32-row tiles, cap-128 regs, both slots (K=1024), frag-contiguous B ----------------
// flat grid 1056 = 3 v x 11 y x 32 b, XCD-swizzled.
__global__ __launch_bounds__(256, 4) void fc2_fused(
    const short* __restrict__ Hs, const short* __restrict__ W2f_l,
    const float* __restrict__ b2_l, float* __restrict__ T,
    short* __restrict__ Tb16, float* __restrict__ Gnext,
    const int* __restrict__ IDX, const float* __restrict__ GV, int lastL)
{
    int i = blockIdx.x;
    int low = i & 7, rest = i >> 3;
    int v = rest % 3, ghi = rest / 3;        // v in [0,3), ghi in [0,44)
    int g = ghi * 8 + low;                   // [0,352)
    int y = g % 11, b = g / 11;
    int m0 = y * 32, n0 = v * 128;
    int tid = threadIdx.x;
    int wave = tid >> 6, lane = tid & 63, quad = lane >> 4, l16 = lane & 15;
    int wn = wave * 32;
    __shared__ short Al[32][264];   // stride 528B -> 2-way frag reads (16.9 KB)
    int e0 = IDX[2 * b], e1 = IDX[2 * b + 1];
    float gt0 = GV[2 * b], gt1 = GV[2 * b + 1];
    float4v zero4 = {0.f, 0.f, 0.f, 0.f};
    float4v acc[2][2];
    #pragma unroll
    for (int a = 0; a < 2; ++a)
        #pragma unroll
        for (int j = 0; j < 2; ++j) acc[a][j] = zero4;

    int nfr = v * 8 + wave * 2;
    int nf0 = (nfr > 20) ? 20 : nfr;         // clamp: OOB frags loaded but discarded
    int nf1 = (nfr + 1 > 20) ? 20 : nfr + 1;

    int r8 = tid >> 5, c0s = (tid & 31) * 8;
    #pragma unroll
    for (int sc2 = 0; sc2 < 4; ++sc2) {      // phase = (slot, chunk)
        int slot = sc2 >> 1, chunk = sc2 & 1;
        int koff = chunk * 256;
        int ez = slot ? e1 : e0;
        const short* As = Hs + ((size_t)(b * 2 + slot) * NN) * DHID + koff;
        #pragma unroll
        for (int a = 0; a < 4; ++a) {
            int rr = a * 8 + r8;
            int gr = m0 + rr; if (gr > NN - 1) gr = NN - 1;   // clamp slack rows
            *(uint4*)&Al[rr][c0s] = *(const uint4*)(As + (size_t)gr * DHID + c0s);
        }
        __syncthreads();
        const short* B0 = W2f_l + (size_t)ez * E2S + (size_t)nf0 * F2S + (size_t)chunk * 4096 + lane * 8;
        const short* B1 = W2f_l + (size_t)ez * E2S + (size_t)nf1 * F2S + (size_t)chunk * 4096 + lane * 8;
        short8 c0 = *(const short8*)(B0);
        short8 c1 = *(const short8*)(B1);
        #pragma unroll
        for (int ks = 0; ks < 8; ++ks) {
            short8 n0v, n1v;
            if (ks < 7) {
                n0v = *(const short8*)(B0 + (ks + 1) * 512);
                n1v = *(const short8*)(B1 + (ks + 1) * 512);
            }
            int off = ks * 32;
            short8 af[2];
            #pragma unroll
            for (int mi = 0; mi < 2; ++mi) af[mi] = *(const short8*)&Al[mi * 16 + l16][off + quad * 8];
            #pragma unroll
            for (int mi = 0; mi < 2; ++mi) {
                acc[mi][0] = __builtin_amdgcn_mfma_f32_16x16x32_bf16(af[mi], c0, acc[mi][0], 0, 0, 0);
                acc[mi][1] = __builtin_amdgcn_mfma_f32_16x16x32_bf16(af[mi], c1, acc[mi][1], 0, 0, 0);
            }
            if (ks < 7) { c0 = n0v; c1 = n1v; }
        }
        __syncthreads();
    }
    // epilogue: residual + bias, single-writer T + bf16 mirror + G partial sums
    const float* b2e0 = b2_l + (size_t)e0 * LL;
    const float* b2e1 = b2_l + (size_t)e1 * LL;
    float* Tb = T + (size_t)b * NN * LL;
    short* Bt = Tb16 + (size_t)b * NN * LP;
    #pragma unroll
    for (int ni = 0; ni < 2; ++ni) {
        int gl = n0 + wn + ni * 16 + l16;
        float s = 0.f;
        if (gl < LL) {
            float bias = gt0 * b2e0[gl] + gt1 * b2e1[gl];
            #pragma unroll
            for (int mi = 0; mi < 2; ++mi) {
                #pragma unroll
                for (int r = 0; r < 4; ++r) {
                    int gm = m0 + mi * 16 + quad * 4 + r;
                    if (gm < NN) {
                        float vv = acc[mi][ni][r] + bias + Tb[(size_t)gm * LL + gl];
                        if (!lastL) Tb[(size_t)gm * LL + gl] = vv;
                        Bt[(size_t)gm * LP + gl] = f2b(vv);
                        s += vv;
                    }
                }
            }
        }
        s += __shfl_xor(s, 16);
        s += __shfl_xor(s, 32);
        if (!lastL && quad == 0 && gl < LL)
            unsafeAtomicAdd(&Gnext[b * LL + gl], s);
    }
}

// ---------------- projection head: 32-row tiles, 2 barriers, direct-global weights ----------------
__global__ __launch_bounds__(256) void proj_fused(
    const short* __restrict__ Tb16,
    const short* __restrict__ p1wb, const float* __restrict__ p1b,
    const short* __restrict__ p2wb, const float* __restrict__ p2b,
    float* __restrict__ out, const float* __restrict__ LOSS)
{
    __shared__ short Al[32][360];   // 32 x 352 A-tile (stride 360 -> ~2-way banks)
    __shared__ short Hp[32][104];   // 32 x 96 tanh-hidden (stride 104 -> 2-way)
    int m0 = blockIdx.x * 32;
    int tid = threadIdx.x;
    if (blockIdx.x == 0 && tid == 0) out[BPN] = LOSS[0];
    int wave = tid >> 6, lane = tid & 63, quad = lane >> 4, l16 = lane & 15;
    float4v zero4 = {0.f, 0.f, 0.f, 0.f};

    // stage A once: 1408 uint4 (32*352*2B)
    #pragma unroll
    for (int i = 0; i < 6; ++i) {
        int idx = tid + i * 256;
        if (idx < 1408) {
            int r = idx / 44, c = (idx - r * 44) * 8;
            *(uint4*)&Al[r][c] = *(const uint4*)(Tb16 + (size_t)(m0 + r) * LP + c);
        }
    }
    __syncthreads();

    // ---- phase 1: Hp = tanh(A @ p1w^T + p1b). wave: rf = wave&1, cf = (wave>>1)+2j ----
    {
        int rf = wave & 1, cfb = wave >> 1;
        float4v acc1[3];
        #pragma unroll
        for (int j = 0; j < 3; ++j) acc1[j] = zero4;
        const short* B1p0 = p1wb + (size_t)(cfb * 16 + l16) * LP + quad * 8;
        #pragma unroll
        for (int ks = 0; ks < 11; ++ks) {   // barrier-free; B direct-global (L1/L2-served)
            int off = ks * 32;
            short8 af = *(const short8*)&Al[rf * 16 + l16][off + quad * 8];
            #pragma unroll
            for (int j = 0; j < 3; ++j) {
                short8 bf = *(const short8*)(B1p0 + (size_t)j * 32 * LP + off);
                acc1[j] = __builtin_amdgcn_mfma_f32_16x16x32_bf16(af, bf, acc1[j], 0, 0, 0);
            }
        }
        #pragma unroll
        for (int j = 0; j < 3; ++j) {
            int p = (cfb + 2 * j) * 16 + l16;
            float pb = p1b[p];
            #pragma unroll
            for (int r = 0; r < 4; ++r)
                Hp[rf * 16 + quad * 4 + r][p] = f2b(fast_tanh(acc1[j][r] + pb));
        }
    }
    __syncthreads();

    // ---- phase 2 (transposed): c-rows = wave*3+mi frags, node cols; B direct-global ----
    float4v acc2[3][2];
    #pragma unroll
    for (int a = 0; a < 3; ++a)
        #pragma unroll
        for (int j = 0; j < 2; ++j) acc2[a][j] = zero4;
    #pragma unroll
    for (int kc = 0; kc < 3; ++kc) {
        int off = kc * 32 + quad * 8;
        short8 bfv0 = *(const short8*)&Hp[l16][off];
        short8 bfv1 = *(const short8*)&Hp[16 + l16][off];
        #pragma unroll
        for (int mi = 0; mi < 3; ++mi) {
            int cf = wave * 3 + mi;
            short8 af = *(const short8*)(p2wb + (size_t)(cf * 16 + l16) * PP + off);
            acc2[mi][0] = __builtin_amdgcn_mfma_f32_16x16x32_bf16(af, bfv0, acc2[mi][0], 0, 0, 0);
            acc2[mi][1] = __builtin_amdgcn_mfma_f32_16x16x32_bf16(af, bfv1, acc2[mi][1], 0, 0, 0);
        }
    }
    // stores: lane l16 -> consecutive node (64B runs per quad); 321*32 = MROWS exactly
    int bqv[2], ndv[2];
    #pragma unroll
    for (int ni = 0; ni < 2; ++ni) {
        int gm = m0 + ni * 16 + l16;
        int bq = gm / NN;
        bqv[ni] = bq; ndv[ni] = gm - bq * NN;
    }
    #pragma unroll
    for (int mi = 0; mi < 3; ++mi) {
        #pragma unroll
        for (int r = 0; r < 4; ++r) {
            int c = (wave * 3 + mi) * 16 + quad * 4 + r;
            float pb = p2b[c];
            int p = c >> 1;
            if ((r & 1) == 0) {               // c even -> mean
                #pragma unroll
                for (int ni = 0; ni < 2; ++ni) {
                    float v = acc2[mi][ni][r] + pb;
                    out[((size_t)bqv[ni] * PP + p) * NN + ndv[ni]] = v;
                }
            } else {                          // c odd -> std
                #pragma unroll
                for (int ni = 0; ni < 2; ++ni) {
                    float v = acc2[mi][ni][r] + pb;
                    out[BPN + 1 + ((size_t)bqv[ni] * PP + p) * NN + ndv[ni]] = softplus_f(v) + 1e-6f;
                }
            }
        }
    }
}

extern "C" void kernel_launch(void* const* d_in, const int* in_sizes, int n_in,
                              void* d_out, int out_size, void* d_ws, size_t ws_size,
                              hipStream_t stream)
{
    const float* x     = (const float*)d_in[0];
    const float* noise = (const float*)d_in[1];
    const float* wg    = (const float*)d_in[2];
    const float* wn    = (const float*)d_in[3];
    const float* W1    = (const float*)d_in[4];
    const float* b1    = (const float*)d_in[5];
    const float* W2    = (const float*)d_in[6];
    const float* b2    = (const float*)d_in[7];
    const float* p1w   = (const float*)d_in[8];
    const float* p1b   = (const float*)d_in[9];
    const float* p2w   = (const float*)d_in[10];
    const float* p2b   = (const float*)d_in[11];
    float* out = (float*)d_out;

    float* ws   = (float*)d_ws;
    float* T    = ws;                          // STOT fp32 (stride LL)
    float* G0   = T + STOT;                    // BB*LL gate sums (double rotation)
    float* G1   = G0 + BB * LL;
    float* LOSS = G1 + BB * LL;                // 8
    float* GV   = LOSS + 8;                    // 64
    int*   IDX  = (int*)(GV + 64);             // 64
    float* MU   = (float*)(IDX + 64);          // BB*NN
    float* IV   = MU + MROWS;                  // BB*NN
    short* W1f  = (short*)(IV + MROWS);        // NLAYERS*EE*E1S shorts
    short* W2f  = W1f + (size_t)NLAYERS * EE * DHID * LP;  // same byte size as before
    short* p1wb = W2f + (size_t)NLAYERS * EE * LL * DHID;  // 96*LP (K-padded)
    short* p2wb = p1wb + PP * LP;              // 192*96
    short* Tb16 = p2wb + 2 * PP * PP;          // (MROWS+64) x LP bf16 mirror of T
    short* Hs   = Tb16 + (size_t)(MROWS + 64) * LP;  // 64*NN rows + slack x DHID bf16

    prep_kernel<<<1549, 256, 0, stream>>>(x, W1, W2, p1w, p2w, MU, IV, LOSS, G0,
                                          W1f, W2f, p1wb, p2wb);
    revin_tn<<<dim3(BB, 6, 7), 256, 0, stream>>>(x, MU, IV, T, Tb16, G0);

    for (int l = 0; l < NLAYERS; ++l) {
        const float* Gcur = (l == 1) ? G1 : G0;
        float* Gnext      = (l == 1) ? G0 : G1;
        fc1_mfma<<<704, 256, 0, stream>>>(
            Tb16, W1f + (size_t)l * EE * E1S, b1 + (size_t)l * EE * DHID,
            Gcur, Gnext, wg + (size_t)l * LL * EE, wn + (size_t)l * LL * EE,
            noise + (size_t)l * BB * EE, IDX, GV, Hs, LOSS);
        fc2_fused<<<1056, 256, 0, stream>>>(
            Hs, W2f + (size_t)l * EE * E2S, b2 + (size_t)l * EE * LL,
            T, Tb16, Gnext, IDX, GV, (l == NLAYERS - 1) ? 1 : 0);
    }
    proj_fused<<<321, 256, 0, stream>>>(Tb16, p1wb, p1b, p2wb, p2b, out, LOSS);
}

// Round 11
// 293.684 us; speedup vs baseline: 1.3252x; 1.3252x over previous
//
#include <hip/hip_runtime.h>
#include <hip/hip_bf16.h>

#define NLAYERS 3
#define BB 32
#define LL 336
#define LP 352                 // K-padded stride for Tb16 / p1wb (zeros in pad)
#define NN 321
#define EE 4
#define DHID 512
#define PP 96
#define STOT (BB*NN*LL)        // 3451392
#define MROWS (BB*NN)          // 10272
#define BPN ((size_t)BB*PP*NN) // 986112

// fragment-contiguous weight layouts:
// W1f[e][nf=32][ks=11][lane=64][8]  (frag stride 5632, e stride 180224)
// W2f[e][nf=21][ks=16][lane=64][8]  (frag stride 8192, e stride 172032)
#define F1S 5632
#define E1S 180224
#define F2S 8192
#define E2S 172032

typedef __attribute__((ext_vector_type(8))) short short8;
typedef __attribute__((ext_vector_type(4))) float float4v;

union BF { __hip_bfloat16 h; short s; };

__device__ __forceinline__ short f2b(float f) { BF u; u.h = __float2bfloat16(f); return u.s; }

__device__ __forceinline__ float fast_tanh(float y) {
    float e = __expf(2.0f * y);
    return 1.0f - 2.0f / (e + 1.0f);   // exact limits at +-inf
}
__device__ __forceinline__ float gelu_f(float x) {
    return 0.5f * x * (1.0f + fast_tanh(0.7978845608028654f * (x + 0.044715f * x * x * x)));
}
__device__ __forceinline__ float softplus_f(float x) {
    return fmaxf(x, 0.0f) + log1pf(expf(-fabsf(x)));
}

// ---------------- prep: weight transpose->fragment layout + pcvt + RevIN stats + zeroing ----------------
__global__ __launch_bounds__(256) void prep_kernel(
    const float* __restrict__ x, const float* __restrict__ W1, const float* __restrict__ W2,
    const float* __restrict__ p1w, const float* __restrict__ p2w,
    float* __restrict__ MU, float* __restrict__ IV, float* __restrict__ LOSS,
    float* __restrict__ G0, short* __restrict__ W1f, short* __restrict__ W2f,
    short* __restrict__ p1wb, short* __restrict__ p2wb)
{
    __shared__ short Ws[64][72];
    __shared__ float Ss[4][64], Sq[4][64];
    int idx = blockIdx.x, tid = threadIdx.x;
    if (idx < 1152) {
        const float* src; int K, D, KS, bx, by, le;
        if (idx < 576) {
            le = idx / 48; int r = idx % 48;
            src = W1 + (size_t)le * LL * DHID;
            K = LL; D = DHID; KS = LP; bx = r % 8; by = r / 8;
        } else {
            int s2 = idx - 576; le = s2 / 48; int r = s2 % 48;
            src = W2 + (size_t)le * DHID * LL;
            K = DHID; D = LL; KS = DHID; bx = r % 6; by = r / 6;
        }
        int d0 = bx * 64, k0 = by * 64;
        // vectorized stage: 4 iterations of float4 per thread (64x64 tile)
        #pragma unroll
        for (int it = 0; it < 4; ++it) {
            int ki = (tid >> 4) + it * 16;
            int dj = (tid & 15) * 4;
            int k = k0 + ki, d = d0 + dj;
            float4 v = make_float4(0.f, 0.f, 0.f, 0.f);
            if (k < K) {
                const float* sp = src + (size_t)k * D + d;
                if (d + 3 < D) v = *(const float4*)sp;
                else {
                    if (d     < D) v.x = sp[0];
                    if (d + 1 < D) v.y = sp[1];
                    if (d + 2 < D) v.z = sp[2];
                    if (d + 3 < D) v.w = sp[3];
                }
            }
            union { short s[4]; uint2 u; } pk4;
            pk4.s[0] = f2b(v.x); pk4.s[1] = f2b(v.y); pk4.s[2] = f2b(v.z); pk4.s[3] = f2b(v.w);
            *(uint2*)&Ws[ki][dj] = pk4.u;
        }
        __syncthreads();
        int di = tid >> 2, d = d0 + di;
        if (d >= D) return;
        #pragma unroll
        for (int kp = 0; kp < 2; ++kp) {
            int kj = ((tid & 3) + 4 * kp) * 8;
            int k = k0 + kj;
            if (k >= KS) continue;
            union { short s[8]; uint4 u; } pk;
            #pragma unroll
            for (int j = 0; j < 8; ++j) pk.s[j] = Ws[kj + j][di];
            int nf = d >> 4;
            int ks = k >> 5;
            int l  = (((k >> 3) & 3) << 4) | (d & 15);
            if (idx < 576) {   // W1f: [le][nf][ks(11)][l][8]
                size_t o = (size_t)le * E1S + ((size_t)(nf * 11 + ks) * 64 + l) * 8;
                *(uint4*)&W1f[o] = pk.u;
            } else {           // W2f: [le][nf][ks(16)][l][8]
                size_t o = (size_t)le * E2S + ((size_t)(nf * 16 + ks) * 64 + l) * 8;
                *(uint4*)&W2f[o] = pk.u;
            }
        }
    } else if (idx < 1344) {
        int q = idx - 1152;
        int b = q / 6, nt = q % 6;
        if (tid < 56) G0[q * 56 + tid] = 0.0f;      // 192*56 = BB*LL exactly
        if (q == 0 && tid < 8) LOSS[tid] = 0.0f;
        int ni = tid & 63, lc = tid >> 6;
        int n = nt * 64 + ni;
        float s = 0.f, ss = 0.f;
        if (n < NN) {
            const float* xp = x + ((size_t)b * LL + lc * 84) * NN + n;
            for (int l = 0; l < 84; ++l, xp += NN) {
                float v = *xp; s += v; ss = fmaf(v, v, ss);
            }
        }
        Ss[lc][ni] = s; Sq[lc][ni] = ss;
        __syncthreads();
        if (lc == 0 && n < NN) {
            float st = ((Ss[0][ni] + Ss[1][ni]) + Ss[2][ni]) + Ss[3][ni];
            float sq = ((Sq[0][ni] + Sq[1][ni]) + Sq[2][ni]) + Sq[3][ni];
            float mu  = st * (1.0f / LL);
            float var = sq * (1.0f / LL) - mu * mu;   // ddof=0
            MU[b * NN + n] = mu;
            IV[b * NN + n] = 1.0f / sqrtf(var + 1e-5f);
        }
    } else {
        int i = (idx - 1344) * 256 + tid;
        if (i < PP * LP) {
            int n = i / LP, k = i - n * LP;
            p1wb[i] = (k < LL) ? f2b(p1w[n * LL + k]) : (short)0;
        } else if (i < PP * LP + 2 * PP * PP) {
            int j = i - PP * LP;
            p2wb[j] = f2b(p2w[j]);
        }
    }
}

// ---------------- RevIN transpose+normalize + layer-0 gate-sum accumulation ----------------
__global__ __launch_bounds__(256) void revin_tn(
    const float* __restrict__ x, const float* __restrict__ MU, const float* __restrict__ IV,
    float* __restrict__ T, short* __restrict__ Tb16, float* __restrict__ G0)
{
    int b = blockIdx.x, nt = blockIdx.y, lt = blockIdx.z;
    int n0 = nt * 64, l0 = lt * 48;
    __shared__ float Ls[48][65];
    __shared__ float Vs[48][65];
    int tid = threadIdx.x;
    #pragma unroll
    for (int i = 0; i < 12; ++i) {
        int lin = tid + i * 256;
        int li = lin >> 6, ni = lin & 63;
        int n = n0 + ni;
        Ls[li][ni] = (n < NN) ? x[((size_t)b * LL + l0 + li) * NN + n] : 0.f;
    }
    __syncthreads();
    int r = tid >> 2, q = tid & 3;
    int n = n0 + r;
    bool valid = (n < NN);
    float mu = 0.f, iv = 0.f;
    if (valid) { mu = MU[b * NN + n]; iv = IV[b * NN + n]; }
    size_t rowf = (size_t)(b * NN + (valid ? n : 0)) * LL + l0;
    size_t rowb = (size_t)(b * NN + (valid ? n : 0)) * LP + l0;
    #pragma unroll
    for (int k = 0; k < 3; ++k) {
        int c = (q + 4 * k) * 4;
        float4 v;
        v.x = (Ls[c    ][r] - mu) * iv;
        v.y = (Ls[c + 1][r] - mu) * iv;
        v.z = (Ls[c + 2][r] - mu) * iv;
        v.w = (Ls[c + 3][r] - mu) * iv;
        Vs[c][r] = v.x; Vs[c + 1][r] = v.y; Vs[c + 2][r] = v.z; Vs[c + 3][r] = v.w;
        if (valid) {
            *(float4*)&T[rowf + c] = v;
            union { short s[4]; uint2 u; } pk;
            pk.s[0] = f2b(v.x); pk.s[1] = f2b(v.y); pk.s[2] = f2b(v.z); pk.s[3] = f2b(v.w);
            *(uint2*)&Tb16[rowb + c] = pk.u;
        }
    }
    if (valid && lt == 6 && q == 3) {   // zero the K-pad cols 336..352
        size_t base = (size_t)(b * NN + n) * LP;
        *(uint4*)&Tb16[base + 336] = make_uint4(0, 0, 0, 0);
        *(uint4*)&Tb16[base + 344] = make_uint4(0, 0, 0, 0);
    }
    __syncthreads();
    if (tid < 48) {   // column sums over this block's 64 nodes -> G0 (SUMS, zeroed by prep)
        float s = 0.f;
        #pragma unroll 8
        for (int rr = 0; rr < 64; ++rr) s += Vs[tid][rr];
        unsafeAtomicAdd(&G0[b * LL + l0 + tid], s);
    }
}

// ---------------- loss scratch (aliases fc1's A-tile LDS) ----------------
struct LossSM {
    float pc2[BB][EE][2], pn2[BB][EE][2];
    float sc[BB][EE], sn[BB][EE], sy[BB][EE], sg[BB][EE];
    float sti[BB], sto[BB];
    float simp[EE], sload[EE];
};

// full-batch aux loss; 256-thread block. Leading barrier protects the alias.
// (Gnext zeroing is spread across fc1 blocks i<42, NOT here.)
__device__ void loss_tail(LossSM* S, const float* __restrict__ Gcur,
                          const float* __restrict__ wgL, const float* __restrict__ wnL,
                          const float* __restrict__ noiseL, float* __restrict__ LOSS, int tid)
{
    __syncthreads();
    {
        int bb = tid >> 3, ee = (tid >> 1) & 3, sub = tid & 1;
        float c = 0.f, nr = 0.f;
        const float* gp = Gcur + bb * LL;
        for (int l = sub * 168; l < sub * 168 + 168; ++l) {
            float gv = gp[l] * (1.0f / NN);
            c  = fmaf(gv, wgL[l * EE + ee], c);
            nr = fmaf(gv, wnL[l * EE + ee], nr);
        }
        S->pc2[bb][ee][sub] = c; S->pn2[bb][ee][sub] = nr;
    }
    __syncthreads();
    if (tid < 128) {
        int bb = tid >> 2, ee = tid & 3;
        float c  = S->pc2[bb][ee][0] + S->pc2[bb][ee][1];
        float nr = S->pn2[bb][ee][0] + S->pn2[bb][ee][1];
        float ns = softplus_f(nr) + 1e-2f;
        S->sc[bb][ee] = c; S->sn[bb][ee] = ns;
        S->sy[bb][ee] = fmaf(noiseL[bb * EE + ee], ns, c);
    }
    __syncthreads();
    if (tid < 128 && (tid & 3) == 0) {
        int bb = tid >> 2;
        float v[4];
        #pragma unroll
        for (int i = 0; i < 4; ++i) v[i] = S->sy[bb][i];
        int i0 = 0;
        for (int i = 1; i < 4; ++i) if (v[i] > v[i0]) i0 = i;
        int i1 = -1;
        for (int i = 0; i < 4; ++i) { if (i == i0) continue; if (i1 < 0 || v[i] > v[i1]) i1 = i; }
        float m3 = -1e30f;
        for (int i = 0; i < 4; ++i) { if (i == i0 || i == i1) continue; if (v[i] > m3) m3 = v[i]; }
        float e1 = expf(v[i1] - v[i0]);
        float invd = 1.0f / (1.0f + e1);
        #pragma unroll
        for (int i = 0; i < 4; ++i) S->sg[bb][i] = 0.f;
        S->sg[bb][i0] = invd;
        S->sg[bb][i1] = e1 * invd;
        S->sti[bb] = m3;       // (k+1)-th value
        S->sto[bb] = v[i1];    // k-th value
    }
    __syncthreads();
    if (tid < EE) {
        int ee = tid;
        float imp = 0.f, ld = 0.f;
        for (int bb2 = 0; bb2 < BB; ++bb2) {
            imp += S->sg[bb2][ee];
            float thr = (S->sy[bb2][ee] > S->sti[bb2]) ? S->sti[bb2] : S->sto[bb2];
            float z = (S->sc[bb2][ee] - thr) / S->sn[bb2][ee];
            ld += 0.5f * (1.0f + erff(z * 0.7071067811865476f));
        }
        S->simp[ee] = imp; S->sload[ee] = ld;
    }
    __syncthreads();
    if (tid == 0) {
        float aux = 0.f;
        {
            float m = (S->simp[0] + S->simp[1] + S->simp[2] + S->simp[3]) * 0.25f;
            float var = 0.f;
            for (int i = 0; i < 4; ++i) { float d = S->simp[i] - m; var += d * d; }
            var *= (1.0f / 3.0f);
            aux += var / (m * m + 1e-10f);
        }
        {
            float m = (S->sload[0] + S->sload[1] + S->sload[2] + S->sload[3]) * 0.25f;
            float var = 0.f;
            for (int i = 0; i < 4; ++i) { float d = S->sload[i] - m; var += d * d; }
            var *= (1.0f / 3.0f);
            aux += var / (m * m + 1e-10f);
        }
        LOSS[0] += 0.01f * aux;
    }
}

// ---------------- FC1 (R9-exact): 32-row tiles, one slot per block, prefetch-1 ----------------
// flat grid 1408 = 4 v x 11 y x 32 b (XCD-swizzled). v = (slot<<1)|xt, n0 = xt*256, acc 2x4.
__global__ __launch_bounds__(256, 4) void fc1_mfma(
    const short* __restrict__ Tb16, const short* __restrict__ W1f_l,
    const float* __restrict__ b1_l,
    const float* __restrict__ Gcur, float* __restrict__ Gnext,
    const float* __restrict__ wgL, const float* __restrict__ wnL,
    const float* __restrict__ noiseL,
    int* __restrict__ IDX, float* __restrict__ GV,
    short* __restrict__ Hs, float* __restrict__ LOSS)
{
    int i = blockIdx.x;
    int low = i & 7, rest = i >> 3;
    int v = rest & 3, ghi = rest >> 2;       // v in [0,4), ghi in [0,44)
    int g = ghi * 8 + low;                   // [0,352)
    int y = g % 11, b = g / 11;
    int xt = v & 1, slot = v >> 1;
    int m0 = y * 32, n0 = xt * 256;
    int tid = threadIdx.x;
    int wave = tid >> 6, lane = tid & 63, quad = lane >> 4, l16 = lane & 15;
    __shared__ __align__(16) short Al[32][360];   // stride 720B -> ~2-way banks (23 KB)
    __shared__ float redc[4][4], redn[4][4];
    // spread Gnext zeroing across 42 blocks (42*256 = BB*LL), overlapped with staging
    if (i < 42) Gnext[i * 256 + tid] = 0.0f;
    {   // stage 32 x 352 A tile: 1408 uint4; clamp rows >= NN to NN-1 (avoid slack reads)
        #pragma unroll
        for (int it = 0; it < 6; ++it) {
            int idx = tid + it * 256;
            if (idx < 1408) {
                int r = idx / 44, c = (idx - r * 44) * 8;
                int gr = m0 + r; if (gr > NN - 1) gr = NN - 1;
                *(uint4*)&Al[r][c] = *(const uint4*)(Tb16 + ((size_t)b * NN + gr) * LP + c);
            }
        }
    }
    // gating partials: ALL threads (l = tid, tid+256), wave-reduce -> LDS
    {
        float pce[4] = {0.f,0.f,0.f,0.f}, pne[4] = {0.f,0.f,0.f,0.f};
        const float* gp = Gcur + b * LL;
        #pragma unroll
        for (int pass = 0; pass < 2; ++pass) {
            int l = tid + pass * 256;
            if (l < LL) {
                float gv = gp[l] * (1.0f / NN);
                #pragma unroll
                for (int e2 = 0; e2 < 4; ++e2) {
                    pce[e2] = fmaf(gv, wgL[l * EE + e2], pce[e2]);
                    pne[e2] = fmaf(gv, wnL[l * EE + e2], pne[e2]);
                }
            }
        }
        #pragma unroll
        for (int off = 32; off >= 1; off >>= 1) {
            #pragma unroll
            for (int e2 = 0; e2 < 4; ++e2) {
                pce[e2] += __shfl_xor(pce[e2], off);
                pne[e2] += __shfl_xor(pne[e2], off);
            }
        }
        if (lane == 0) {
            #pragma unroll
            for (int e2 = 0; e2 < 4; ++e2) { redc[wave][e2] = pce[e2]; redn[wave][e2] = pne[e2]; }
        }
    }
    __syncthreads();
    // redundant per-thread finalize (deterministic -> uniform)
    int e; float gt;
    {
        float vv[4];
        #pragma unroll
        for (int e2 = 0; e2 < 4; ++e2) {
            float c  = ((redc[0][e2] + redc[1][e2]) + redc[2][e2]) + redc[3][e2];
            float nr = ((redn[0][e2] + redn[1][e2]) + redn[2][e2]) + redn[3][e2];
            float ns = softplus_f(nr) + 1e-2f;
            vv[e2] = fmaf(noiseL[b * EE + e2], ns, c);
        }
        int i0 = 0;
        #pragma unroll
        for (int e2 = 1; e2 < 4; ++e2) if (vv[e2] > vv[i0]) i0 = e2;
        int i1 = -1;
        #pragma unroll
        for (int e2 = 0; e2 < 4; ++e2) { if (e2 == i0) continue; if (i1 < 0 || vv[e2] > vv[i1]) i1 = e2; }
        float e1v = expf(vv[i1] - vv[i0]);
        float invd = 1.0f / (1.0f + e1v);
        e  = slot ? i1 : i0;
        gt = slot ? (e1v * invd) : invd;
        if (y == 0 && v == 0 && tid == 0) {   // publish for fc2 (one block per b)
            IDX[2 * b] = i0; IDX[2 * b + 1] = i1;
            GV[2 * b] = invd; GV[2 * b + 1] = e1v * invd;
        }
    }

    // B fragments: wave-contiguous 1KB reads, depth-1 prefetch. nf = xt*16 + wave*4 + ni
    const short* Bf = W1f_l + (size_t)(e * 32 + xt * 16 + wave * 4) * F1S + lane * 8;
    float4v zero4 = {0.f, 0.f, 0.f, 0.f};
    float4v acc[2][4];
    #pragma unroll
    for (int a = 0; a < 2; ++a)
        #pragma unroll
        for (int j = 0; j < 4; ++j) acc[a][j] = zero4;

    short8 bc[4];
    #pragma unroll
    for (int j = 0; j < 4; ++j) bc[j] = *(const short8*)(Bf + j * F1S);
    #pragma unroll
    for (int ks = 0; ks < 11; ++ks) {
        short8 bn[4];
        if (ks < 10) {
            int o = (ks + 1) * 512;
            #pragma unroll
            for (int j = 0; j < 4; ++j) bn[j] = *(const short8*)(Bf + j * F1S + o);
        }
        int off = ks * 32;
        short8 af[2];
        #pragma unroll
        for (int mi = 0; mi < 2; ++mi) af[mi] = *(const short8*)&Al[mi * 16 + l16][off + quad * 8];
        #pragma unroll
        for (int mi = 0; mi < 2; ++mi) {
            acc[mi][0] = __builtin_amdgcn_mfma_f32_16x16x32_bf16(af[mi], bc[0], acc[mi][0], 0, 0, 0);
            acc[mi][1] = __builtin_amdgcn_mfma_f32_16x16x32_bf16(af[mi], bc[1], acc[mi][1], 0, 0, 0);
            acc[mi][2] = __builtin_amdgcn_mfma_f32_16x16x32_bf16(af[mi], bc[2], acc[mi][2], 0, 0, 0);
            acc[mi][3] = __builtin_amdgcn_mfma_f32_16x16x32_bf16(af[mi], bc[3], acc[mi][3], 0, 0, 0);
        }
        if (ks < 10) {
            #pragma unroll
            for (int j = 0; j < 4; ++j) bc[j] = bn[j];
        }
    }
    const float* bb = b1_l + (size_t)e * DHID;
    int wn4 = wave * 64;
    float bias[4];
    #pragma unroll
    for (int ni = 0; ni < 4; ++ni) bias[ni] = bb[n0 + wn4 + ni * 16 + l16];
    short* Ho = Hs + (size_t)(b * 2 + slot) * NN * DHID;
    #pragma unroll
    for (int mi = 0; mi < 2; ++mi) {
        #pragma unroll
        for (int r = 0; r < 4; ++r) {
            int gm = m0 + mi * 16 + quad * 4 + r;   // C/D: col=lane&15, row=quad*4+reg
            if (gm >= NN) continue;
            #pragma unroll
            for (int ni = 0; ni < 4; ++ni) {
                int gd = n0 + wn4 + ni * 16 + l16;
                float vv = acc[mi][ni][r] + bias[ni];
                Ho[(size_t)gm * DHID + gd] = f2b(gt * gelu_f(vv));
            }
        }
    }
    if (i == 0) loss_tail((LossSM*)&Al[0][0], Gcur, wgL, wnL, noiseL, LOSS, tid);
}

// ---------------- FC2: 32-row tiles, cap-128 regs, both slots (K=1024), frag-contiguous B ----------------
// flat grid 1056 = 3 v x 11 y x 32 b, XCD-swizzled.
__global__ __launch_bounds__(256, 4) void fc2_fused(
    const short* __restrict__ Hs, const short* __restrict__ W2f_l,
    const float* __restrict__ b2_l, float* __restrict__ T,
    short* __restrict__ Tb16, float* __restrict__ Gnext,
    const int* __restrict__ IDX, const float* __restrict__ GV, int lastL)
{
    int i = blockIdx.x;
    int low = i & 7, rest = i >> 3;
    int v = rest % 3, ghi = rest / 3;        // v in [0,3), ghi in [0,44)
    int g = ghi * 8 + low;                   // [0,352)
    int y = g % 11, b = g / 11;
    int m0 = y * 32, n0 = v * 128;
    int tid = threadIdx.x;
    int wave = tid >> 6, lane = tid & 63, quad = lane >> 4, l16 = lane & 15;
    int wn = wave * 32;
    __shared__ short Al[32][264];   // stride 528B -> 2-way frag reads (16.9 KB)
    int e0 = IDX[2 * b], e1 = IDX[2 * b + 1];
    float gt0 = GV[2 * b], gt1 = GV[2 * b + 1];
    float4v zero4 = {0.f, 0.f, 0.f, 0.f};
    float4v acc[2][2];
    #pragma unroll
    for (int a = 0; a < 2; ++a)
        #pragma unroll
        for (int j = 0; j < 2; ++j) acc[a][j] = zero4;

    int nfr = v * 8 + wave * 2;
    int nf0 = (nfr > 20) ? 20 : nfr;         // clamp: OOB frags loaded but discarded
    int nf1 = (nfr + 1 > 20) ? 20 : nfr + 1;

    int r8 = tid >> 5, c0s = (tid & 31) * 8;
    #pragma unroll
    for (int sc2 = 0; sc2 < 4; ++sc2) {      // phase = (slot, chunk)
        int slot = sc2 >> 1, chunk = sc2 & 1;
        int koff = chunk * 256;
        int ez = slot ? e1 : e0;
        const short* As = Hs + ((size_t)(b * 2 + slot) * NN) * DHID + koff;
        #pragma unroll
        for (int a = 0; a < 4; ++a) {
            int rr = a * 8 + r8;
            int gr = m0 + rr; if (gr > NN - 1) gr = NN - 1;   // clamp slack rows
            *(uint4*)&Al[rr][c0s] = *(const uint4*)(As + (size_t)gr * DHID + c0s);
        }
        __syncthreads();
        const short* B0 = W2f_l + (size_t)ez * E2S + (size_t)nf0 * F2S + (size_t)chunk * 4096 + lane * 8;
        const short* B1 = W2f_l + (size_t)ez * E2S + (size_t)nf1 * F2S + (size_t)chunk * 4096 + lane * 8;
        short8 c0 = *(const short8*)(B0);
        short8 c1 = *(const short8*)(B1);
        #pragma unroll
        for (int ks = 0; ks < 8; ++ks) {
            short8 n0v, n1v;
            if (ks < 7) {
                n0v = *(const short8*)(B0 + (ks + 1) * 512);
                n1v = *(const short8*)(B1 + (ks + 1) * 512);
            }
            int off = ks * 32;
            short8 af[2];
            #pragma unroll
            for (int mi = 0; mi < 2; ++mi) af[mi] = *(const short8*)&Al[mi * 16 + l16][off + quad * 8];
            #pragma unroll
            for (int mi = 0; mi < 2; ++mi) {
                acc[mi][0] = __builtin_amdgcn_mfma_f32_16x16x32_bf16(af[mi], c0, acc[mi][0], 0, 0, 0);
                acc[mi][1] = __builtin_amdgcn_mfma_f32_16x16x32_bf16(af[mi], c1, acc[mi][1], 0, 0, 0);
            }
            if (ks < 7) { c0 = n0v; c1 = n1v; }
        }
        __syncthreads();
    }
    // epilogue: residual + bias, single-writer T + bf16 mirror + G partial sums
    const float* b2e0 = b2_l + (size_t)e0 * LL;
    const float* b2e1 = b2_l + (size_t)e1 * LL;
    float* Tb = T + (size_t)b * NN * LL;
    short* Bt = Tb16 + (size_t)b * NN * LP;
    #pragma unroll
    for (int ni = 0; ni < 2; ++ni) {
        int gl = n0 + wn + ni * 16 + l16;
        float s = 0.f;
        if (gl < LL) {
            float bias = gt0 * b2e0[gl] + gt1 * b2e1[gl];
            #pragma unroll
            for (int mi = 0; mi < 2; ++mi) {
                #pragma unroll
                for (int r = 0; r < 4; ++r) {
                    int gm = m0 + mi * 16 + quad * 4 + r;
                    if (gm < NN) {
                        float vv = acc[mi][ni][r] + bias + Tb[(size_t)gm * LL + gl];
                        if (!lastL) Tb[(size_t)gm * LL + gl] = vv;
                        Bt[(size_t)gm * LP + gl] = f2b(vv);
                        s += vv;
                    }
                }
            }
        }
        s += __shfl_xor(s, 16);
        s += __shfl_xor(s, 32);
        if (!lastL && quad == 0 && gl < LL)
            unsafeAtomicAdd(&Gnext[b * LL + gl], s);
    }
}

// ---------------- projection head: 32-row tiles, 2 barriers, direct-global weights ----------------
__global__ __launch_bounds__(256) void proj_fused(
    const short* __restrict__ Tb16,
    const short* __restrict__ p1wb, const float* __restrict__ p1b,
    const short* __restrict__ p2wb, const float* __restrict__ p2b,
    float* __restrict__ out, const float* __restrict__ LOSS)
{
    __shared__ short Al[32][360];   // 32 x 352 A-tile (stride 360 -> ~2-way banks)
    __shared__ short Hp[32][104];   // 32 x 96 tanh-hidden (stride 104 -> 2-way)
    int m0 = blockIdx.x * 32;
    int tid = threadIdx.x;
    if (blockIdx.x == 0 && tid == 0) out[BPN] = LOSS[0];
    int wave = tid >> 6, lane = tid & 63, quad = lane >> 4, l16 = lane & 15;
    float4v zero4 = {0.f, 0.f, 0.f, 0.f};

    // stage A once: 1408 uint4 (32*352*2B)
    #pragma unroll
    for (int i = 0; i < 6; ++i) {
        int idx = tid + i * 256;
        if (idx < 1408) {
            int r = idx / 44, c = (idx - r * 44) * 8;
            *(uint4*)&Al[r][c] = *(const uint4*)(Tb16 + (size_t)(m0 + r) * LP + c);
        }
    }
    __syncthreads();

    // ---- phase 1: Hp = tanh(A @ p1w^T + p1b). wave: rf = wave&1, cf = (wave>>1)+2j ----
    {
        int rf = wave & 1, cfb = wave >> 1;
        float4v acc1[3];
        #pragma unroll
        for (int j = 0; j < 3; ++j) acc1[j] = zero4;
        const short* B1p0 = p1wb + (size_t)(cfb * 16 + l16) * LP + quad * 8;
        #pragma unroll
        for (int ks = 0; ks < 11; ++ks) {   // barrier-free; B direct-global (L1/L2-served)
            int off = ks * 32;
            short8 af = *(const short8*)&Al[rf * 16 + l16][off + quad * 8];
            #pragma unroll
            for (int j = 0; j < 3; ++j) {
                short8 bf = *(const short8*)(B1p0 + (size_t)j * 32 * LP + off);
                acc1[j] = __builtin_amdgcn_mfma_f32_16x16x32_bf16(af, bf, acc1[j], 0, 0, 0);
            }
        }
        #pragma unroll
        for (int j = 0; j < 3; ++j) {
            int p = (cfb + 2 * j) * 16 + l16;
            float pb = p1b[p];
            #pragma unroll
            for (int r = 0; r < 4; ++r)
                Hp[rf * 16 + quad * 4 + r][p] = f2b(fast_tanh(acc1[j][r] + pb));
        }
    }
    __syncthreads();

    // ---- phase 2 (transposed): c-rows = wave*3+mi frags, node cols; B direct-global ----
    float4v acc2[3][2];
    #pragma unroll
    for (int a = 0; a < 3; ++a)
        #pragma unroll
        for (int j = 0; j < 2; ++j) acc2[a][j] = zero4;
    #pragma unroll
    for (int kc = 0; kc < 3; ++kc) {
        int off = kc * 32 + quad * 8;
        short8 bfv0 = *(const short8*)&Hp[l16][off];
        short8 bfv1 = *(const short8*)&Hp[16 + l16][off];
        #pragma unroll
        for (int mi = 0; mi < 3; ++mi) {
            int cf = wave * 3 + mi;
            short8 af = *(const short8*)(p2wb + (size_t)(cf * 16 + l16) * PP + off);
            acc2[mi][0] = __builtin_amdgcn_mfma_f32_16x16x32_bf16(af, bfv0, acc2[mi][0], 0, 0, 0);
            acc2[mi][1] = __builtin_amdgcn_mfma_f32_16x16x32_bf16(af, bfv1, acc2[mi][1], 0, 0, 0);
        }
    }
    // stores: lane l16 -> consecutive node (64B runs per quad); 321*32 = MROWS exactly
    int bqv[2], ndv[2];
    #pragma unroll
    for (int ni = 0; ni < 2; ++ni) {
        int gm = m0 + ni * 16 + l16;
        int bq = gm / NN;
        bqv[ni] = bq; ndv[ni] = gm - bq * NN;
    }
    #pragma unroll
    for (int mi = 0; mi < 3; ++mi) {
        #pragma unroll
        for (int r = 0; r < 4; ++r) {
            int c = (wave * 3 + mi) * 16 + quad * 4 + r;
            float pb = p2b[c];
            int p = c >> 1;
            if ((r & 1) == 0) {               // c even -> mean
                #pragma unroll
                for (int ni = 0; ni < 2; ++ni) {
                    float v = acc2[mi][ni][r] + pb;
                    out[((size_t)bqv[ni] * PP + p) * NN + ndv[ni]] = v;
                }
            } else {                          // c odd -> std
                #pragma unroll
                for (int ni = 0; ni < 2; ++ni) {
                    float v = acc2[mi][ni][r] + pb;
                    out[BPN + 1 + ((size_t)bqv[ni] * PP + p) * NN + ndv[ni]] = softplus_f(v) + 1e-6f;
                }
            }
        }
    }
}

extern "C" void kernel_launch(void* const* d_in, const int* in_sizes, int n_in,
                              void* d_out, int out_size, void* d_ws, size_t ws_size,
                              hipStream_t stream)
{
    const float* x     = (const float*)d_in[0];
    const float* noise = (const float*)d_in[1];
    const float* wg    = (const float*)d_in[2];
    const float* wn    = (const float*)d_in[3];
    const float* W1    = (const float*)d_in[4];
    const float* b1    = (const float*)d_in[5];
    const float* W2    = (const float*)d_in[6];
    const float* b2    = (const float*)d_in[7];
    const float* p1w   = (const float*)d_in[8];
    const float* p1b   = (const float*)d_in[9];
    const float* p2w   = (const float*)d_in[10];
    const float* p2b   = (const float*)d_in[11];
    float* out = (float*)d_out;

    float* ws   = (float*)d_ws;
    float* T    = ws;                          // STOT fp32 (stride LL)
    float* G0   = T + STOT;                    // BB*LL gate sums (double rotation)
    float* G1   = G0 + BB * LL;
    float* LOSS = G1 + BB * LL;                // 8
    float* GV   = LOSS + 8;                    // 64
    int*   IDX  = (int*)(GV + 64);             // 64
    float* MU   = (float*)(IDX + 64);          // BB*NN
    float* IV   = MU + MROWS;                  // BB*NN
    short* W1f  = (short*)(IV + MROWS);        // NLAYERS*EE*E1S shorts
    short* W2f  = W1f + (size_t)NLAYERS * EE * DHID * LP;  // same byte size as before
    short* p1wb = W2f + (size_t)NLAYERS * EE * LL * DHID;  // 96*LP (K-padded)
    short* p2wb = p1wb + PP * LP;              // 192*96
    short* Tb16 = p2wb + 2 * PP * PP;          // (MROWS+64) x LP bf16 mirror of T
    short* Hs   = Tb16 + (size_t)(MROWS + 64) * LP;  // 64*NN rows + slack x DHID bf16

    prep_kernel<<<1549, 256, 0, stream>>>(x, W1, W2, p1w, p2w, MU, IV, LOSS, G0,
                                          W1f, W2f, p1wb, p2wb);
    revin_tn<<<dim3(BB, 6, 7), 256, 0, stream>>>(x, MU, IV, T, Tb16, G0);

    for (int l = 0; l < NLAYERS; ++l) {
        const float* Gcur = (l == 1) ? G1 : G0;
        float* Gnext      = (l == 1) ? G0 : G1;
        fc1_mfma<<<1408, 256, 0, stream>>>(
            Tb16, W1f + (size_t)l * EE * E1S, b1 + (size_t)l * EE * DHID,
            Gcur, Gnext, wg + (size_t)l * LL * EE, wn + (size_t)l * LL * EE,
            noise + (size_t)l * BB * EE, IDX, GV, Hs, LOSS);
        fc2_fused<<<1056, 256, 0, stream>>>(
            Hs, W2f + (size_t)l * EE * E2S, b2 + (size_t)l * EE * LL,
            T, Tb16, Gnext, IDX, GV, (l == NLAYERS - 1) ? 1 : 0);
    }
    proj_fused<<<321, 256, 0, stream>>>(Tb16, p1wb, p1b, p2wb, p2b, out, LOSS);
}